// Round 1
// baseline (109.724 us; speedup 1.0000x reference)
//
#include <hip/hip_runtime.h>
#include <hip/hip_bf16.h>

#define NB 64
#define NE 40000
#define DIM 200
#define NL 100
#define EBLK 64
#define NTHREADS 256
#define LOG2E 1.4426950408889634f

// Phase-1 arrays (score_l) and phase-2 arrays (score_n) share one LDS region.
union SMem {
    struct {
        unsigned short eT[DIM][EBLK];  // bf16 E^T chunk: 200*64*2 = 25600 B
        float e1rT[DIM][NB];           // f32 (e1*r)^T:   200*64*4 = 51200 B
    } p1;
    struct {
        float xsT[NL][EBLK];           // num_lit[e,l]*s[l]       25600 B
        float asT[NL][NB];             // (n_h[b,l]-c[l])*s[l]    25600 B
        float wT[NL][NB];              // nf_weights[r_idx[b],l]  25600 B
    } p2;
};

__device__ __forceinline__ unsigned short f2bf(float f) {
    unsigned int u = __float_as_uint(f);
    unsigned int r = (u + 0x7fffu + ((u >> 16) & 1u)) >> 16;  // RNE
    return (unsigned short)r;
}
__device__ __forceinline__ float bf_lo(unsigned int u) {
    return __uint_as_float(u << 16);
}
__device__ __forceinline__ float bf_hi(unsigned int u) {
    return __uint_as_float(u & 0xffff0000u);
}

__global__ __launch_bounds__(NTHREADS, 2)
void DistMult_KBLN_79164837200204_kernel(
    const int* __restrict__ e1_idx, const int* __restrict__ r_idx,
    const float* __restrict__ Ew, const float* __restrict__ Rw,
    const float* __restrict__ num_lit, const float* __restrict__ cvec,
    const float* __restrict__ var, const float* __restrict__ nfw,
    float* __restrict__ out)
{
    __shared__ SMem sm;
    __shared__ float sS[NL];  // sqrt(log2e / var[l])

    const int t = threadIdx.x;
    const int e0 = blockIdx.x * EBLK;

    // ---- stage: s[l] ----
    if (t < NL) sS[t] = sqrtf(LOG2E / var[t]);

    // ---- stage phase 1: E^T chunk (bf16) ----
    {
        const float4* E4 = (const float4*)Ew;
        for (int f4 = t; f4 < EBLK * (DIM / 4); f4 += NTHREADS) {
            int e = f4 / (DIM / 4);
            int d4 = f4 % (DIM / 4);
            float4 v = E4[(e0 + e) * (DIM / 4) + d4];
            int d = d4 * 4;
            sm.p1.eT[d + 0][e] = f2bf(v.x);
            sm.p1.eT[d + 1][e] = f2bf(v.y);
            sm.p1.eT[d + 2][e] = f2bf(v.z);
            sm.p1.eT[d + 3][e] = f2bf(v.w);
        }
    }
    // ---- stage phase 1: (e1*r)^T (f32) ----
    {
        const float4* E4 = (const float4*)Ew;
        const float4* R4 = (const float4*)Rw;
        for (int f4 = t; f4 < NB * (DIM / 4); f4 += NTHREADS) {
            int b = f4 / (DIM / 4);
            int d4 = f4 % (DIM / 4);
            int ib = e1_idx[b];
            int rb = r_idx[b];
            float4 a = E4[ib * (DIM / 4) + d4];
            float4 r = R4[rb * (DIM / 4) + d4];
            int d = d4 * 4;
            sm.p1.e1rT[d + 0][b] = a.x * r.x;
            sm.p1.e1rT[d + 1][b] = a.y * r.y;
            sm.p1.e1rT[d + 2][b] = a.z * r.z;
            sm.p1.e1rT[d + 3][b] = a.w * r.w;
        }
    }
    __syncthreads();

    // ---- phase 1 compute: acc[k][j] = sum_d e1r[b=4ty+k][d] * E[e=e0+4tx+j][d]
    const int tx = t & 15;
    const int ty = t >> 4;
    float acc[4][4] = {};

    #pragma unroll 4
    for (int d = 0; d < DIM; ++d) {
        uint2 u = *(const uint2*)&sm.p1.eT[d][4 * tx];
        float4 br = *(const float4*)&sm.p1.e1rT[d][4 * ty];
        float ej[4] = { bf_lo(u.x), bf_hi(u.x), bf_lo(u.y), bf_hi(u.y) };
        float bk[4] = { br.x, br.y, br.z, br.w };
        #pragma unroll
        for (int k = 0; k < 4; ++k)
            #pragma unroll
            for (int j = 0; j < 4; ++j)
                acc[k][j] = fmaf(bk[k], ej[j], acc[k][j]);
    }
    __syncthreads();  // phase-1 reads done; safe to overwrite union

    // ---- stage phase 2 ----
    {
        const float4* N4 = (const float4*)num_lit;
        for (int f4 = t; f4 < EBLK * (NL / 4); f4 += NTHREADS) {
            int e = f4 / (NL / 4);
            int l4 = f4 % (NL / 4);
            float4 v = N4[(e0 + e) * (NL / 4) + l4];
            int l = l4 * 4;
            sm.p2.xsT[l + 0][e] = v.x * sS[l + 0];
            sm.p2.xsT[l + 1][e] = v.y * sS[l + 1];
            sm.p2.xsT[l + 2][e] = v.z * sS[l + 2];
            sm.p2.xsT[l + 3][e] = v.w * sS[l + 3];
        }
        const float4* C4 = (const float4*)cvec;
        for (int f4 = t; f4 < NB * (NL / 4); f4 += NTHREADS) {
            int b = f4 / (NL / 4);
            int l4 = f4 % (NL / 4);
            float4 v = N4[e1_idx[b] * (NL / 4) + l4];
            float4 cc = C4[l4];
            int l = l4 * 4;
            sm.p2.asT[l + 0][b] = (v.x - cc.x) * sS[l + 0];
            sm.p2.asT[l + 1][b] = (v.y - cc.y) * sS[l + 1];
            sm.p2.asT[l + 2][b] = (v.z - cc.z) * sS[l + 2];
            sm.p2.asT[l + 3][b] = (v.w - cc.w) * sS[l + 3];
        }
        const float4* W4 = (const float4*)nfw;
        for (int f4 = t; f4 < NB * (NL / 4); f4 += NTHREADS) {
            int b = f4 / (NL / 4);
            int l4 = f4 % (NL / 4);
            float4 v = W4[r_idx[b] * (NL / 4) + l4];
            int l = l4 * 4;
            sm.p2.wT[l + 0][b] = v.x;
            sm.p2.wT[l + 1][b] = v.y;
            sm.p2.wT[l + 2][b] = v.z;
            sm.p2.wT[l + 3][b] = v.w;
        }
    }
    __syncthreads();

    // ---- phase 2 compute: acc += sum_l w[b,l] * exp2(-((as[b,l]-xs[e,l])^2))
    #pragma unroll 2
    for (int l = 0; l < NL; ++l) {
        float4 xs = *(const float4*)&sm.p2.xsT[l][4 * tx];
        float4 as = *(const float4*)&sm.p2.asT[l][4 * ty];
        float4 w  = *(const float4*)&sm.p2.wT[l][4 * ty];
        float xj[4] = { xs.x, xs.y, xs.z, xs.w };
        float ak[4] = { as.x, as.y, as.z, as.w };
        float wk[4] = { w.x,  w.y,  w.z,  w.w  };
        #pragma unroll
        for (int k = 0; k < 4; ++k)
            #pragma unroll
            for (int j = 0; j < 4; ++j) {
                float m = ak[k] - xj[j];
                float p = __builtin_amdgcn_exp2f(-(m * m));
                acc[k][j] = fmaf(p, wk[k], acc[k][j]);
            }
    }

    // ---- epilogue: sigmoid + coalesced float4 stores ----
    #pragma unroll
    for (int k = 0; k < 4; ++k) {
        int b = 4 * ty + k;
        float4 o;
        float* op = (float*)&o;
        #pragma unroll
        for (int j = 0; j < 4; ++j) {
            float x = acc[k][j];
            float ex = __builtin_amdgcn_exp2f(-LOG2E * x);
            op[j] = __builtin_amdgcn_rcpf(1.0f + ex);
        }
        *(float4*)&out[b * NE + e0 + 4 * tx] = o;
    }
}

extern "C" void kernel_launch(void* const* d_in, const int* in_sizes, int n_in,
                              void* d_out, int out_size, void* d_ws, size_t ws_size,
                              hipStream_t stream) {
    const int*   e1_idx  = (const int*)d_in[0];
    const int*   r_idx   = (const int*)d_in[1];
    const float* Ew      = (const float*)d_in[2];
    const float* Rw      = (const float*)d_in[3];
    const float* num_lit = (const float*)d_in[4];
    const float* cvec    = (const float*)d_in[5];
    const float* var     = (const float*)d_in[6];
    const float* nfw     = (const float*)d_in[7];
    float* out = (float*)d_out;

    dim3 grid(NE / EBLK);   // 625 blocks, exact (40000 = 625*64)
    dim3 block(NTHREADS);
    DistMult_KBLN_79164837200204_kernel<<<grid, block, 0, stream>>>(
        e1_idx, r_idx, Ew, Rw, num_lit, cvec, var, nfw, out);
}

// Round 2
// 80.126 us; speedup vs baseline: 1.3694x; 1.3694x over previous
//
#include <hip/hip_runtime.h>

#define NB 64
#define NE 40000
#define DIM 200
#define NL 100
#define EBLK 64
#define NTHREADS 256
#define DH (DIM / 2)   // 100 d-rows per phase-1 half
#define D4H (DH / 4)   // 25 float4 chunks per half-row
#define LH (NL / 2)    // 50 l-rows per phase-2 half
#define L2H (LH / 2)   // 25 float2 chunks per half-row
#define LOG2E 1.4426950408889634f

// Phase-1 half-arrays and phase-2 half-arrays share one 38.4 KB LDS union.
// All layouts are transposed (d-major / l-major) so COMPUTE reads are
// conflict-free; STAGING loops map consecutive lanes -> consecutive columns
// so writes are consecutive dwords (conflict-free).
union SMem {
    struct {
        unsigned int eTp[DH][EBLK / 2];  // packed bf16 pair (e=2p, 2p+1): 12800 B
        float e1rT[DH][NB];              // f32 (e1*r)^T half:            25600 B
    } p1;
    struct {
        float xsT[LH][EBLK];             // num_lit[e,l]*s[l]             12800 B
        float asT[LH][NB];               // (n_h[b,l]-c[l])*s[l]          12800 B
        float wT[LH][NB];                // nf_weights[r_idx[b],l]        12800 B
    } p2;
};

__device__ __forceinline__ unsigned int f2bf(float f) {
    unsigned int u = __float_as_uint(f);
    return (u + 0x7fffu + ((u >> 16) & 1u)) >> 16;  // RNE
}
__device__ __forceinline__ float bf_lo(unsigned int u) {
    return __uint_as_float(u << 16);
}
__device__ __forceinline__ float bf_hi(unsigned int u) {
    return __uint_as_float(u & 0xffff0000u);
}

__global__ __launch_bounds__(NTHREADS, 4)
void DistMult_KBLN_79164837200204_kernel(
    const int* __restrict__ e1_idx, const int* __restrict__ r_idx,
    const float* __restrict__ Ew, const float* __restrict__ Rw,
    const float* __restrict__ num_lit, const float* __restrict__ cvec,
    const float* __restrict__ var, const float* __restrict__ nfw,
    float* __restrict__ out)
{
    __shared__ SMem sm;
    __shared__ float sS[NL];  // sqrt(log2e / var[l])

    const int t = threadIdx.x;
    const int e0 = blockIdx.x * EBLK;
    const int tx = t & 15;
    const int ty = t >> 4;

    if (t < NL) sS[t] = sqrtf(LOG2E / var[t]);

    float acc[4][4] = {};

    const float4* E4 = (const float4*)Ew;
    const float4* R4 = (const float4*)Rw;

    // ================= phase 1: score_l, two d-halves =================
    #pragma unroll 1
    for (int h = 0; h < 2; ++h) {
        // stage E^T chunk as packed bf16 pairs; lanes own consecutive pairs p
        for (int f = t; f < (EBLK / 2) * D4H; f += NTHREADS) {
            int p = f & 31;
            int d4 = f >> 5;
            float4 va = E4[(e0 + 2 * p)     * (DIM / 4) + h * D4H + d4];
            float4 vb = E4[(e0 + 2 * p + 1) * (DIM / 4) + h * D4H + d4];
            sm.p1.eTp[4 * d4 + 0][p] = f2bf(va.x) | (f2bf(vb.x) << 16);
            sm.p1.eTp[4 * d4 + 1][p] = f2bf(va.y) | (f2bf(vb.y) << 16);
            sm.p1.eTp[4 * d4 + 2][p] = f2bf(va.z) | (f2bf(vb.z) << 16);
            sm.p1.eTp[4 * d4 + 3][p] = f2bf(va.w) | (f2bf(vb.w) << 16);
        }
        // stage (e1*r)^T f32; lanes own consecutive b
        for (int f = t; f < NB * D4H; f += NTHREADS) {
            int b = f & 63;
            int d4 = f >> 6;
            float4 a = E4[e1_idx[b] * (DIM / 4) + h * D4H + d4];
            float4 r = R4[r_idx[b]  * (DIM / 4) + h * D4H + d4];
            sm.p1.e1rT[4 * d4 + 0][b] = a.x * r.x;
            sm.p1.e1rT[4 * d4 + 1][b] = a.y * r.y;
            sm.p1.e1rT[4 * d4 + 2][b] = a.z * r.z;
            sm.p1.e1rT[4 * d4 + 3][b] = a.w * r.w;
        }
        __syncthreads();

        #pragma unroll 4
        for (int d = 0; d < DH; ++d) {
            uint2 u = *(const uint2*)&sm.p1.eTp[d][2 * tx];
            float4 br = *(const float4*)&sm.p1.e1rT[d][4 * ty];
            float ej[4] = { bf_lo(u.x), bf_hi(u.x), bf_lo(u.y), bf_hi(u.y) };
            float bk[4] = { br.x, br.y, br.z, br.w };
            #pragma unroll
            for (int k = 0; k < 4; ++k)
                #pragma unroll
                for (int j = 0; j < 4; ++j)
                    acc[k][j] = fmaf(bk[k], ej[j], acc[k][j]);
        }
        __syncthreads();  // compute done; union half can be overwritten
    }

    // ================= phase 2: score_n, two l-halves =================
    const float2* N2 = (const float2*)num_lit;
    const float2* C2 = (const float2*)cvec;
    const float2* W2 = (const float2*)nfw;

    #pragma unroll 1
    for (int h = 0; h < 2; ++h) {
        // xsT: lanes own consecutive e
        for (int f = t; f < EBLK * L2H; f += NTHREADS) {
            int e = f & 63;
            int l2 = f >> 6;
            float2 v = N2[(e0 + e) * (NL / 2) + h * L2H + l2];
            int lg = h * LH + 2 * l2;
            sm.p2.xsT[2 * l2 + 0][e] = v.x * sS[lg + 0];
            sm.p2.xsT[2 * l2 + 1][e] = v.y * sS[lg + 1];
        }
        // asT: lanes own consecutive b
        for (int f = t; f < NB * L2H; f += NTHREADS) {
            int b = f & 63;
            int l2 = f >> 6;
            float2 v = N2[e1_idx[b] * (NL / 2) + h * L2H + l2];
            float2 cc = C2[h * L2H + l2];
            int lg = h * LH + 2 * l2;
            sm.p2.asT[2 * l2 + 0][b] = (v.x - cc.x) * sS[lg + 0];
            sm.p2.asT[2 * l2 + 1][b] = (v.y - cc.y) * sS[lg + 1];
        }
        // wT: lanes own consecutive b
        for (int f = t; f < NB * L2H; f += NTHREADS) {
            int b = f & 63;
            int l2 = f >> 6;
            float2 v = W2[r_idx[b] * (NL / 2) + h * L2H + l2];
            sm.p2.wT[2 * l2 + 0][b] = v.x;
            sm.p2.wT[2 * l2 + 1][b] = v.y;
        }
        __syncthreads();

        #pragma unroll 2
        for (int l = 0; l < LH; ++l) {
            float4 xs = *(const float4*)&sm.p2.xsT[l][4 * tx];
            float4 as = *(const float4*)&sm.p2.asT[l][4 * ty];
            float4 w  = *(const float4*)&sm.p2.wT[l][4 * ty];
            float xj[4] = { xs.x, xs.y, xs.z, xs.w };
            float ak[4] = { as.x, as.y, as.z, as.w };
            float wk[4] = { w.x,  w.y,  w.z,  w.w  };
            #pragma unroll
            for (int k = 0; k < 4; ++k)
                #pragma unroll
                for (int j = 0; j < 4; ++j) {
                    float m = ak[k] - xj[j];
                    float p = __builtin_amdgcn_exp2f(-(m * m));
                    acc[k][j] = fmaf(p, wk[k], acc[k][j]);
                }
        }
        __syncthreads();
    }

    // ================= epilogue: sigmoid + coalesced stores =================
    #pragma unroll
    for (int k = 0; k < 4; ++k) {
        int b = 4 * ty + k;
        float4 o;
        float* op = (float*)&o;
        #pragma unroll
        for (int j = 0; j < 4; ++j) {
            float x = acc[k][j];
            float ex = __builtin_amdgcn_exp2f(-LOG2E * x);
            op[j] = __builtin_amdgcn_rcpf(1.0f + ex);
        }
        *(float4*)&out[b * NE + e0 + 4 * tx] = o;
    }
}

extern "C" void kernel_launch(void* const* d_in, const int* in_sizes, int n_in,
                              void* d_out, int out_size, void* d_ws, size_t ws_size,
                              hipStream_t stream) {
    const int*   e1_idx  = (const int*)d_in[0];
    const int*   r_idx   = (const int*)d_in[1];
    const float* Ew      = (const float*)d_in[2];
    const float* Rw      = (const float*)d_in[3];
    const float* num_lit = (const float*)d_in[4];
    const float* cvec    = (const float*)d_in[5];
    const float* var     = (const float*)d_in[6];
    const float* nfw     = (const float*)d_in[7];
    float* out = (float*)d_out;

    dim3 grid(NE / EBLK);   // 625 blocks, exact
    dim3 block(NTHREADS);
    DistMult_KBLN_79164837200204_kernel<<<grid, block, 0, stream>>>(
        e1_idx, r_idx, Ew, Rw, num_lit, cvec, var, nfw, out);
}

// Round 3
// 73.609 us; speedup vs baseline: 1.4906x; 1.0885x over previous
//
#include <hip/hip_runtime.h>

#define NB 64
#define NE 40000
#define DIM 200
#define NL 100
#define EBLK 32
#define NTHREADS 256
#define LOG2E 1.4426950408889634f

// Phase-1 d-quarter arrays and phase-2 l-quarter arrays share one LDS union.
// Transposed (d-major / l-major) layouts: compute reads are conflict-free
// (float4 rows for the e-side, broadcast float2 for the b-side); staging
// writes map consecutive lanes -> consecutive columns (conflict-free).
union SMem {
    struct {
        float eT[52][36];    // E^T d-quarter, padded 32->36: 7488 B
        float e1rT[52][64];  // (e1*r)^T d-quarter:          13312 B
    } p1;                    //                         sum: 20800 B
    struct {
        float xsT[28][32];   // num_lit[e,l]*s[l]:            3584 B
        float asT[28][64];   // (n_h[b,l]-c[l])*s[l]:         7168 B
        float wT[28][64];    // nf_weights[r_idx[b],l]:       7168 B
    } p2;                    //                         sum: 17920 B
};

__global__ __launch_bounds__(NTHREADS, 5)
void DistMult_KBLN_79164837200204_kernel(
    const int* __restrict__ e1_idx, const int* __restrict__ r_idx,
    const float* __restrict__ Ew, const float* __restrict__ Rw,
    const float* __restrict__ num_lit, const float* __restrict__ cvec,
    const float* __restrict__ var, const float* __restrict__ nfw,
    float* __restrict__ out)
{
    __shared__ SMem sm;
    __shared__ float sS[NL];    // sqrt(log2e / var[l])
    __shared__ int sIdxE[NB], sIdxR[NB];

    const int t = threadIdx.x;
    const int e0 = blockIdx.x * EBLK;
    const int tx = t & 7;       // 8 groups * 4e = 32 e
    const int ty = t >> 3;      // 32 groups * 2b = 64 b

    if (t < NL) sS[t] = sqrtf(LOG2E / var[t]);
    if (t < NB) { sIdxE[t] = e1_idx[t]; sIdxR[t] = r_idx[t]; }
    __syncthreads();

    // acc2[j] = {acc for b=2*ty, acc for b=2*ty+1} at e = e0 + 4*tx + j
    float2 acc2[4] = {};

    const float4* E4 = (const float4*)Ew;   // row stride 50 float4
    const float4* R4 = (const float4*)Rw;

    // ============ phase 1: score_l, 4 d-quarters (52/52/52/44) ============
    #pragma unroll
    for (int q = 0; q < 4; ++q) {
        const int od4 = q * 13;             // float4 offset in row
        const int nd4 = (q < 3) ? 13 : 11;  // float4 count this quarter
        // stage E^T (f32): lanes own consecutive e
        for (int f = t; f < EBLK * nd4; f += NTHREADS) {
            int e = f & 31;
            int d4 = f >> 5;
            float4 v = E4[(e0 + e) * 50 + od4 + d4];
            sm.p1.eT[4 * d4 + 0][e] = v.x;
            sm.p1.eT[4 * d4 + 1][e] = v.y;
            sm.p1.eT[4 * d4 + 2][e] = v.z;
            sm.p1.eT[4 * d4 + 3][e] = v.w;
        }
        // stage (e1*r)^T (f32): lanes own consecutive b
        for (int f = t; f < NB * nd4; f += NTHREADS) {
            int b = f & 63;
            int d4 = f >> 6;
            float4 a = E4[sIdxE[b] * 50 + od4 + d4];
            float4 r = R4[sIdxR[b] * 50 + od4 + d4];
            sm.p1.e1rT[4 * d4 + 0][b] = a.x * r.x;
            sm.p1.e1rT[4 * d4 + 1][b] = a.y * r.y;
            sm.p1.e1rT[4 * d4 + 2][b] = a.z * r.z;
            sm.p1.e1rT[4 * d4 + 3][b] = a.w * r.w;
        }
        __syncthreads();

        const int nd = 4 * nd4;  // 52 or 44
        #pragma unroll 4
        for (int d = 0; d < nd; ++d) {
            float4 ej = *(const float4*)&sm.p1.eT[d][4 * tx];
            float2 bk = *(const float2*)&sm.p1.e1rT[d][2 * ty];
            acc2[0].x = fmaf(bk.x, ej.x, acc2[0].x);
            acc2[0].y = fmaf(bk.y, ej.x, acc2[0].y);
            acc2[1].x = fmaf(bk.x, ej.y, acc2[1].x);
            acc2[1].y = fmaf(bk.y, ej.y, acc2[1].y);
            acc2[2].x = fmaf(bk.x, ej.z, acc2[2].x);
            acc2[2].y = fmaf(bk.y, ej.z, acc2[2].y);
            acc2[3].x = fmaf(bk.x, ej.w, acc2[3].x);
            acc2[3].y = fmaf(bk.y, ej.w, acc2[3].y);
        }
        __syncthreads();  // quarter consumed; union may be overwritten
    }

    // ============ phase 2: score_n, 4 l-quarters (28/28/28/16) ============
    const float4* N4 = (const float4*)num_lit;  // row stride 25 float4
    const float4* C4 = (const float4*)cvec;
    const float4* W4 = (const float4*)nfw;

    #pragma unroll
    for (int q = 0; q < 4; ++q) {
        const int ol  = q * 28;
        const int ol4 = q * 7;
        const int nl4 = (q < 3) ? 7 : 4;
        // xsT: lanes own consecutive e
        for (int f = t; f < EBLK * nl4; f += NTHREADS) {
            int e = f & 31;
            int l4 = f >> 5;
            float4 v = N4[(e0 + e) * 25 + ol4 + l4];
            int lg = ol + 4 * l4;
            sm.p2.xsT[4 * l4 + 0][e] = v.x * sS[lg + 0];
            sm.p2.xsT[4 * l4 + 1][e] = v.y * sS[lg + 1];
            sm.p2.xsT[4 * l4 + 2][e] = v.z * sS[lg + 2];
            sm.p2.xsT[4 * l4 + 3][e] = v.w * sS[lg + 3];
        }
        // asT: lanes own consecutive b
        for (int f = t; f < NB * nl4; f += NTHREADS) {
            int b = f & 63;
            int l4 = f >> 6;
            float4 v = N4[sIdxE[b] * 25 + ol4 + l4];
            float4 cc = C4[ol4 + l4];
            int lg = ol + 4 * l4;
            sm.p2.asT[4 * l4 + 0][b] = (v.x - cc.x) * sS[lg + 0];
            sm.p2.asT[4 * l4 + 1][b] = (v.y - cc.y) * sS[lg + 1];
            sm.p2.asT[4 * l4 + 2][b] = (v.z - cc.z) * sS[lg + 2];
            sm.p2.asT[4 * l4 + 3][b] = (v.w - cc.w) * sS[lg + 3];
        }
        // wT: lanes own consecutive b
        for (int f = t; f < NB * nl4; f += NTHREADS) {
            int b = f & 63;
            int l4 = f >> 6;
            float4 v = W4[sIdxR[b] * 25 + ol4 + l4];
            sm.p2.wT[4 * l4 + 0][b] = v.x;
            sm.p2.wT[4 * l4 + 1][b] = v.y;
            sm.p2.wT[4 * l4 + 2][b] = v.z;
            sm.p2.wT[4 * l4 + 3][b] = v.w;
        }
        __syncthreads();

        const int nl = 4 * nl4;  // 28 or 16
        #pragma unroll 4
        for (int l = 0; l < nl; ++l) {
            float4 xs = *(const float4*)&sm.p2.xsT[l][4 * tx];
            float2 as = *(const float2*)&sm.p2.asT[l][2 * ty];
            float2 w  = *(const float2*)&sm.p2.wT[l][2 * ty];
            float xj[4] = { xs.x, xs.y, xs.z, xs.w };
            #pragma unroll
            for (int j = 0; j < 4; ++j) {
                float m0 = as.x - xj[j];
                float m1 = as.y - xj[j];
                float p0 = __builtin_amdgcn_exp2f(-(m0 * m0));
                float p1 = __builtin_amdgcn_exp2f(-(m1 * m1));
                acc2[j].x = fmaf(p0, w.x, acc2[j].x);
                acc2[j].y = fmaf(p1, w.y, acc2[j].y);
            }
        }
        __syncthreads();
    }

    // ============ epilogue: sigmoid + float4 stores ============
    {
        float4 o0, o1;
        float* p0 = (float*)&o0;
        float* p1 = (float*)&o1;
        #pragma unroll
        for (int j = 0; j < 4; ++j) {
            float ex0 = __builtin_amdgcn_exp2f(-LOG2E * acc2[j].x);
            float ex1 = __builtin_amdgcn_exp2f(-LOG2E * acc2[j].y);
            p0[j] = __builtin_amdgcn_rcpf(1.0f + ex0);
            p1[j] = __builtin_amdgcn_rcpf(1.0f + ex1);
        }
        size_t b0 = 2 * ty;
        *(float4*)&out[b0 * NE + e0 + 4 * tx] = o0;
        *(float4*)&out[(b0 + 1) * NE + e0 + 4 * tx] = o1;
    }
}

extern "C" void kernel_launch(void* const* d_in, const int* in_sizes, int n_in,
                              void* d_out, int out_size, void* d_ws, size_t ws_size,
                              hipStream_t stream) {
    const int*   e1_idx  = (const int*)d_in[0];
    const int*   r_idx   = (const int*)d_in[1];
    const float* Ew      = (const float*)d_in[2];
    const float* Rw      = (const float*)d_in[3];
    const float* num_lit = (const float*)d_in[4];
    const float* cvec    = (const float*)d_in[5];
    const float* var     = (const float*)d_in[6];
    const float* nfw     = (const float*)d_in[7];
    float* out = (float*)d_out;

    dim3 grid(NE / EBLK);   // 1250 blocks, exact (40000 = 1250*32)
    dim3 block(NTHREADS);
    DistMult_KBLN_79164837200204_kernel<<<grid, block, 0, stream>>>(
        e1_idx, r_idx, Ew, Rw, num_lit, cvec, var, nfw, out);
}

// Round 6
// 60.579 us; speedup vs baseline: 1.8112x; 1.2151x over previous
//
#include <hip/hip_runtime.h>

#define NB 64
#define NE 40000
#define DIM 200
#define NL 100
#define EBLK 32
#define NTHREADS 256
#define D4 50          // float4 per E row
#define L4 25          // float4 per num_lit row
#define LOG2E 1.4426950408889634f

#define WS_E1R 0       // bf16 [64][224] (e1*r, zero-padded K): 28672 B

typedef float f32x4 __attribute__((ext_vector_type(4)));
typedef short bf16x8 __attribute__((ext_vector_type(8)));

__device__ __forceinline__ unsigned int f2bf(float f) {
    unsigned int u = __float_as_uint(f);
    return (u + 0x7fffu + ((u >> 16) & 1u)) >> 16;  // RNE
}
__device__ __forceinline__ unsigned int packbf(float a, float b) {
    return f2bf(a) | (f2bf(b) << 16);
}

// ---------------- pre-kernel: bake bf16 e1*r into d_ws ----------------
__global__ void DistMult_prep_kernel(
    const int* __restrict__ e1_idx, const int* __restrict__ r_idx,
    const float* __restrict__ Ew, const float* __restrict__ Rw,
    unsigned char* __restrict__ ws)
{
    const int t = blockIdx.x * NTHREADS + threadIdx.x;  // grid 8*256
    unsigned int* e1r = (unsigned int*)(ws + WS_E1R);   // 112 uint per row
    const float4* E4 = (const float4*)Ew;
    const float4* R4 = (const float4*)Rw;

    // e1r bf16 [64][224]: 64 b x 28 chunks of 8 d (chunks 25..27 zero pad)
    for (int f = t; f < NB * 28; f += 8 * NTHREADS) {
        int b = f / 28, c = f % 28;
        uint4 st = {0u, 0u, 0u, 0u};
        if (c < 25) {
            float4 a0 = E4[(size_t)e1_idx[b] * D4 + 2 * c];
            float4 a1 = E4[(size_t)e1_idx[b] * D4 + 2 * c + 1];
            float4 r0 = R4[(size_t)r_idx[b] * D4 + 2 * c];
            float4 r1 = R4[(size_t)r_idx[b] * D4 + 2 * c + 1];
            st.x = packbf(a0.x * r0.x, a0.y * r0.y);
            st.y = packbf(a0.z * r0.z, a0.w * r0.w);
            st.z = packbf(a1.x * r1.x, a1.y * r1.y);
            st.w = packbf(a1.z * r1.z, a1.w * r1.w);
        }
        *(uint4*)(e1r + (size_t)b * 112 + c * 4) = st;
    }
}

// ---------------- main kernel ----------------
// BISECT arm A: phase 1 = MFMA + layout probe + scatter (r5), handed off to
// phase 2 + epilogue = r3 VERBATIM (the code that passed at absmax 0.0039).
union SMem {
    struct {
        unsigned short A[NB * 128];     // bf16 [64][128] swizzled: 16384 B
        unsigned short Bm[EBLK * 128];  // bf16 [32][128] swizzled:  8192 B
    } p1;
    struct {
        float xsT[28][32];   // num_lit[e,l]*s[l]:            3584 B
        float asT[28][64];   // (n_h[b,l]-c[l])*s[l]:         7168 B
        float wT[28][64];    // nf_weights[r_idx[b],l]:       7168 B
    } p2;
    float scat[NB * 33];     // acc transpose buffer:         8448 B
};

__global__ __launch_bounds__(NTHREADS, 4)
void DistMult_KBLN_79164837200204_kernel(
    const int* __restrict__ e1_idx, const int* __restrict__ r_idx,
    const float* __restrict__ Ew, const float* __restrict__ num_lit,
    const float* __restrict__ cvec, const float* __restrict__ var,
    const float* __restrict__ nfw,
    const unsigned char* __restrict__ ws, float* __restrict__ out)
{
    __shared__ SMem sm;
    __shared__ float sS[NL];
    __shared__ int sIdxE[NB], sIdxR[NB];

    const int t = threadIdx.x;
    const int e0 = blockIdx.x * EBLK;
    const int L = t & 63, w = t >> 6;
    const int l15 = L & 15, lq = L >> 4;

    if (t < NL) sS[t] = sqrtf(LOG2E / var[t]);
    if (t < NB) { sIdxE[t] = e1_idx[t]; sIdxR[t] = r_idx[t]; }

    // ======== layout probe: discover true (b,e) of each acc slot ========
    unsigned short* pA = (unsigned short*)sm.p1.A;   // row stride 32
    unsigned short* pB = (unsigned short*)sm.p1.Bm;
    for (int i = t; i < 1024; i += NTHREADS) ((unsigned int*)pA)[i] = 0u;
    for (int i = t; i < 512;  i += NTHREADS) ((unsigned int*)pB)[i] = 0u;
    __syncthreads();
    if (t < 64) {
        pA[t * 32]     = (unsigned short)f2bf(256.0f * t);
        pA[t * 32 + 1] = (unsigned short)f2bf(1.0f);
    } else if (t < 96) {
        int e = t - 64;
        pB[e * 32]     = (unsigned short)f2bf(1.0f);
        pB[e * 32 + 1] = (unsigned short)f2bf((float)e);
    }
    __syncthreads();
    int ib0[4], ib1[4];
    {
        bf16x8 afp = *(const bf16x8*)(pA + (16 * w + l15) * 32 + lq * 8);
        bf16x8 b0p = *(const bf16x8*)(pB + l15 * 32 + lq * 8);
        bf16x8 b1p = *(const bf16x8*)(pB + (16 + l15) * 32 + lq * 8);
        f32x4 z = {0.f, 0.f, 0.f, 0.f};
        f32x4 p0 = __builtin_amdgcn_mfma_f32_16x16x32_bf16(afp, b0p, z, 0, 0, 0);
        f32x4 p1 = __builtin_amdgcn_mfma_f32_16x16x32_bf16(afp, b1p, z, 0, 0, 0);
        #pragma unroll
        for (int r = 0; r < 4; ++r) { ib0[r] = (int)p0[r]; ib1[r] = (int)p1[r]; }
    }
    __syncthreads();

    f32x4 acc0 = {0.f, 0.f, 0.f, 0.f};
    f32x4 acc1 = {0.f, 0.f, 0.f, 0.f};

    const float4* E4 = (const float4*)Ew;
    const uint4* wsA = (const uint4*)(ws + WS_E1R);  // 28 uint4 per row

    // ============ phase 1: score_l via MFMA, 2 K-halves (128 / 96) ============
    #pragma unroll
    for (int h = 0; h < 2; ++h) {
        const int nc = h ? 12 : 16;  // 16B chunks per row this half
        for (int f = t; f < NB * nc; f += NTHREADS) {
            int b = f / nc, c = f % nc;
            uint4 v = wsA[(size_t)b * 28 + h * 16 + c];
            int off = (b * 256 + c * 16) ^ ((b & 7) << 4);
            *(uint4*)((char*)sm.p1.A + off) = v;
        }
        for (int f = t; f < EBLK * nc; f += NTHREADS) {
            int e = f / nc, c = f % nc;
            int dg = h * 128 + c * 8;
            uint4 st = {0u, 0u, 0u, 0u};
            if (dg <= DIM - 8) {
                float4 v0 = E4[(size_t)(e0 + e) * D4 + (dg >> 2)];
                float4 v1 = E4[(size_t)(e0 + e) * D4 + (dg >> 2) + 1];
                st.x = packbf(v0.x, v0.y);
                st.y = packbf(v0.z, v0.w);
                st.z = packbf(v1.x, v1.y);
                st.w = packbf(v1.z, v1.w);
            }
            int off = (e * 256 + c * 16) ^ ((e & 7) << 4);
            *(uint4*)((char*)sm.p1.Bm + off) = st;
        }
        __syncthreads();

        const int nst = h ? 3 : 4;
        const int arow = 16 * w + l15;
        const int aswz = (arow & 7) << 4;
        const int bswz = (l15 & 7) << 4;
        #pragma unroll
        for (int s = 0; s < 4; ++s) {
            if (s < nst) {
                int kb = s * 64 + lq * 16;
                bf16x8 af = *(const bf16x8*)((const char*)sm.p1.A + ((arow * 256 + kb) ^ aswz));
                bf16x8 b0 = *(const bf16x8*)((const char*)sm.p1.Bm + ((l15 * 256 + kb) ^ bswz));
                bf16x8 b1 = *(const bf16x8*)((const char*)sm.p1.Bm + (((16 + l15) * 256 + kb) ^ bswz));
                acc0 = __builtin_amdgcn_mfma_f32_16x16x32_bf16(af, b0, acc0, 0, 0, 0);
                acc1 = __builtin_amdgcn_mfma_f32_16x16x32_bf16(af, b1, acc1, 0, 0, 0);
            }
        }
        __syncthreads();
    }

    // ======== phase 1.5: scatter acc via probed coords, gather at r3 map ====
    #pragma unroll
    for (int r = 0; r < 4; ++r) {
        sm.scat[(ib0[r] >> 8) * 33 + (ib0[r] & 255)] = acc0[r];
        sm.scat[(ib1[r] >> 8) * 33 + (ib1[r] & 255)] = acc1[r];
    }
    __syncthreads();

    // r3 thread mapping: tx = t&7 (4 e each), ty = t>>3 (2 b each)
    const int tx = t & 7;
    const int ty = t >> 3;
    float2 acc2[4];
    #pragma unroll
    for (int j = 0; j < 4; ++j) {
        acc2[j].x = sm.scat[(2 * ty) * 33 + 4 * tx + j];
        acc2[j].y = sm.scat[(2 * ty + 1) * 33 + 4 * tx + j];
    }
    __syncthreads();

    // ============ phase 2: r3 VERBATIM — 4 l-quarters (28/28/28/16) ============
    const float4* N4 = (const float4*)num_lit;
    const float4* C4 = (const float4*)cvec;
    const float4* W4 = (const float4*)nfw;

    #pragma unroll
    for (int q = 0; q < 4; ++q) {
        const int ol  = q * 28;
        const int ol4 = q * 7;
        const int nl4 = (q < 3) ? 7 : 4;
        // xsT: lanes own consecutive e
        for (int f = t; f < EBLK * nl4; f += NTHREADS) {
            int e = f & 31;
            int l4 = f >> 5;
            float4 v = N4[(e0 + e) * 25 + ol4 + l4];
            int lg = ol + 4 * l4;
            sm.p2.xsT[4 * l4 + 0][e] = v.x * sS[lg + 0];
            sm.p2.xsT[4 * l4 + 1][e] = v.y * sS[lg + 1];
            sm.p2.xsT[4 * l4 + 2][e] = v.z * sS[lg + 2];
            sm.p2.xsT[4 * l4 + 3][e] = v.w * sS[lg + 3];
        }
        // asT: lanes own consecutive b
        for (int f = t; f < NB * nl4; f += NTHREADS) {
            int b = f & 63;
            int l4 = f >> 6;
            float4 v = N4[sIdxE[b] * 25 + ol4 + l4];
            float4 cc = C4[ol4 + l4];
            int lg = ol + 4 * l4;
            sm.p2.asT[4 * l4 + 0][b] = (v.x - cc.x) * sS[lg + 0];
            sm.p2.asT[4 * l4 + 1][b] = (v.y - cc.y) * sS[lg + 1];
            sm.p2.asT[4 * l4 + 2][b] = (v.z - cc.z) * sS[lg + 2];
            sm.p2.asT[4 * l4 + 3][b] = (v.w - cc.w) * sS[lg + 3];
        }
        // wT: lanes own consecutive b
        for (int f = t; f < NB * nl4; f += NTHREADS) {
            int b = f & 63;
            int l4 = f >> 6;
            float4 v = W4[sIdxR[b] * 25 + ol4 + l4];
            sm.p2.wT[4 * l4 + 0][b] = v.x;
            sm.p2.wT[4 * l4 + 1][b] = v.y;
            sm.p2.wT[4 * l4 + 2][b] = v.z;
            sm.p2.wT[4 * l4 + 3][b] = v.w;
        }
        __syncthreads();

        const int nl = 4 * nl4;  // 28 or 16
        #pragma unroll 4
        for (int l = 0; l < nl; ++l) {
            float4 xs = *(const float4*)&sm.p2.xsT[l][4 * tx];
            float2 as = *(const float2*)&sm.p2.asT[l][2 * ty];
            float2 w2 = *(const float2*)&sm.p2.wT[l][2 * ty];
            float xj[4] = { xs.x, xs.y, xs.z, xs.w };
            #pragma unroll
            for (int j = 0; j < 4; ++j) {
                float m0 = as.x - xj[j];
                float m1 = as.y - xj[j];
                float p0 = __builtin_amdgcn_exp2f(-(m0 * m0));
                float p1 = __builtin_amdgcn_exp2f(-(m1 * m1));
                acc2[j].x = fmaf(p0, w2.x, acc2[j].x);
                acc2[j].y = fmaf(p1, w2.y, acc2[j].y);
            }
        }
        __syncthreads();
    }

    // ============ epilogue: r3 VERBATIM — sigmoid + float4 stores ============
    {
        float4 o0, o1;
        float* p0 = (float*)&o0;
        float* p1 = (float*)&o1;
        #pragma unroll
        for (int j = 0; j < 4; ++j) {
            float ex0 = __builtin_amdgcn_exp2f(-LOG2E * acc2[j].x);
            float ex1 = __builtin_amdgcn_exp2f(-LOG2E * acc2[j].y);
            p0[j] = __builtin_amdgcn_rcpf(1.0f + ex0);
            p1[j] = __builtin_amdgcn_rcpf(1.0f + ex1);
        }
        size_t b0 = 2 * ty;
        *(float4*)&out[b0 * NE + e0 + 4 * tx] = o0;
        *(float4*)&out[(b0 + 1) * NE + e0 + 4 * tx] = o1;
    }
}

extern "C" void kernel_launch(void* const* d_in, const int* in_sizes, int n_in,
                              void* d_out, int out_size, void* d_ws, size_t ws_size,
                              hipStream_t stream) {
    const int*   e1_idx  = (const int*)d_in[0];
    const int*   r_idx   = (const int*)d_in[1];
    const float* Ew      = (const float*)d_in[2];
    const float* Rw      = (const float*)d_in[3];
    const float* num_lit = (const float*)d_in[4];
    const float* cvec    = (const float*)d_in[5];
    const float* var     = (const float*)d_in[6];
    const float* nfw     = (const float*)d_in[7];
    float* out = (float*)d_out;

    DistMult_prep_kernel<<<8, NTHREADS, 0, stream>>>(
        e1_idx, r_idx, Ew, Rw, (unsigned char*)d_ws);
    DistMult_KBLN_79164837200204_kernel<<<NE / EBLK, NTHREADS, 0, stream>>>(
        e1_idx, r_idx, Ew, num_lit, cvec, var, nfw,
        (const unsigned char*)d_ws, out);
}

// Round 10
// 60.485 us; speedup vs baseline: 1.8141x; 1.0016x over previous
//
#include <hip/hip_runtime.h>

#define NB 64
#define NE 40000
#define DIM 200
#define NL 100
#define EBLK 32
#define NTHREADS 256
#define D4 50          // float4 per E row
#define L4 25          // float4 per num_lit row
#define LOG2E 1.4426950408889634f

#define WS_E1R 0       // bf16 [64][224] (e1*r, zero-padded K): 28672 B (ONLY ws use)

typedef float f32x4 __attribute__((ext_vector_type(4)));
typedef short bf16x8 __attribute__((ext_vector_type(8)));
// SESSION RULE (r4/r5/r7/r8/r9 evidence): NO f32x2 packed arithmetic in
// phase 2 — every build using it failed with build-varying absmax 0.027-0.063
// (v_pk codegen hazard suspected). Scalar fmaf/exp2 only.

__device__ __forceinline__ unsigned int f2bf(float f) {
    unsigned int u = __float_as_uint(f);
    return (u + 0x7fffu + ((u >> 16) & 1u)) >> 16;  // RNE
}
__device__ __forceinline__ unsigned int packbf(float a, float b) {
    return f2bf(a) | (f2bf(b) << 16);
}

// ---------------- pre-kernel: bake bf16 e1*r into d_ws ----------------
__global__ void DistMult_prep_kernel(
    const int* __restrict__ e1_idx, const int* __restrict__ r_idx,
    const float* __restrict__ Ew, const float* __restrict__ Rw,
    unsigned char* __restrict__ ws)
{
    const int t = blockIdx.x * NTHREADS + threadIdx.x;  // grid 8*256
    unsigned int* e1r = (unsigned int*)(ws + WS_E1R);   // 112 uint per row
    const float4* E4 = (const float4*)Ew;
    const float4* R4 = (const float4*)Rw;

    for (int f = t; f < NB * 28; f += 8 * NTHREADS) {
        int b = f / 28, c = f % 28;
        uint4 st = {0u, 0u, 0u, 0u};
        if (c < 25) {
            float4 a0 = E4[(size_t)e1_idx[b] * D4 + 2 * c];
            float4 a1 = E4[(size_t)e1_idx[b] * D4 + 2 * c + 1];
            float4 r0 = R4[(size_t)r_idx[b] * D4 + 2 * c];
            float4 r1 = R4[(size_t)r_idx[b] * D4 + 2 * c + 1];
            st.x = packbf(a0.x * r0.x, a0.y * r0.y);
            st.y = packbf(a0.z * r0.z, a0.w * r0.w);
            st.z = packbf(a1.x * r1.x, a1.y * r1.y);
            st.w = packbf(a1.z * r1.z, a1.w * r1.w);
        }
        *(uint4*)(e1r + (size_t)b * 112 + c * 4) = st;
    }
}

// ---------------- main kernel ----------------
// r6 structure VERBATIM (the passing configuration). Changes vs r6:
//   (1) __launch_bounds__(256,5)  — proven safe in r3; kills dispatch tail
//   (2) bijective XCD-chunked blockIdx swizzle (m204) — L2 locality only
union SMem {
    struct {
        unsigned short A[NB * 128];     // bf16 [64][128] swizzled: 16384 B
        unsigned short Bm[EBLK * 128];  // bf16 [32][128] swizzled:  8192 B
    } p1;
    struct {
        float xsT[28][32];   // num_lit[e,l]*s[l]:            3584 B
        float asT[28][64];   // (n_h[b,l]-c[l])*s[l]:         7168 B
        float wT[28][64];    // nf_weights[r_idx[b],l]:       7168 B
    } p2;
    float scat[NB * 33];     // acc transpose buffer:         8448 B
};

__global__ __launch_bounds__(NTHREADS, 5)
void DistMult_KBLN_79164837200204_kernel(
    const int* __restrict__ e1_idx, const int* __restrict__ r_idx,
    const float* __restrict__ Ew, const float* __restrict__ num_lit,
    const float* __restrict__ cvec, const float* __restrict__ var,
    const float* __restrict__ nfw,
    const unsigned char* __restrict__ ws, float* __restrict__ out)
{
    __shared__ SMem sm;
    __shared__ float sS[NL];
    __shared__ int sIdxE[NB], sIdxR[NB];

    const int t = threadIdx.x;
    // Bijective XCD-chunked swizzle: nwg = 1250, q = 156, r = 2 (m204 form).
    const int nq = (NE / EBLK) >> 3, nr = (NE / EBLK) & 7;
    const int xcd = blockIdx.x & 7, sub = blockIdx.x >> 3;
    const int wg = (xcd < nr ? xcd * (nq + 1) : nr * (nq + 1) + (xcd - nr) * nq) + sub;
    const int e0 = wg * EBLK;

    const int L = t & 63, w = t >> 6;
    const int l15 = L & 15, lq = L >> 4;

    if (t < NL) sS[t] = sqrtf(LOG2E / var[t]);
    if (t < NB) { sIdxE[t] = e1_idx[t]; sIdxR[t] = r_idx[t]; }

    // ======== layout probe: true (b,e) of each acc slot (r6-verified) ========
    unsigned short* pA = (unsigned short*)sm.p1.A;   // row stride 32
    unsigned short* pB = (unsigned short*)sm.p1.Bm;
    for (int i = t; i < 1024; i += NTHREADS) ((unsigned int*)pA)[i] = 0u;
    for (int i = t; i < 512;  i += NTHREADS) ((unsigned int*)pB)[i] = 0u;
    __syncthreads();
    if (t < 64) {
        pA[t * 32]     = (unsigned short)f2bf(256.0f * t);
        pA[t * 32 + 1] = (unsigned short)f2bf(1.0f);
    } else if (t < 96) {
        int e = t - 64;
        pB[e * 32]     = (unsigned short)f2bf(1.0f);
        pB[e * 32 + 1] = (unsigned short)f2bf((float)e);
    }
    __syncthreads();
    int ib0[4], ib1[4];
    {
        bf16x8 afp = *(const bf16x8*)(pA + (16 * w + l15) * 32 + lq * 8);
        bf16x8 b0p = *(const bf16x8*)(pB + l15 * 32 + lq * 8);
        bf16x8 b1p = *(const bf16x8*)(pB + (16 + l15) * 32 + lq * 8);
        f32x4 z = {0.f, 0.f, 0.f, 0.f};
        f32x4 p0 = __builtin_amdgcn_mfma_f32_16x16x32_bf16(afp, b0p, z, 0, 0, 0);
        f32x4 p1 = __builtin_amdgcn_mfma_f32_16x16x32_bf16(afp, b1p, z, 0, 0, 0);
        #pragma unroll
        for (int r = 0; r < 4; ++r) { ib0[r] = (int)p0[r]; ib1[r] = (int)p1[r]; }
    }
    __syncthreads();

    f32x4 acc0 = {0.f, 0.f, 0.f, 0.f};
    f32x4 acc1 = {0.f, 0.f, 0.f, 0.f};

    const float4* E4 = (const float4*)Ew;
    const uint4* wsA = (const uint4*)(ws + WS_E1R);  // 28 uint4 per row

    // ============ phase 1: score_l via MFMA, 2 K-halves (128 / 96) ============
    #pragma unroll
    for (int h = 0; h < 2; ++h) {
        const int nc = h ? 12 : 16;  // 16B chunks per row this half
        for (int f = t; f < NB * nc; f += NTHREADS) {
            int b = f / nc, c = f % nc;
            uint4 v = wsA[(size_t)b * 28 + h * 16 + c];
            int off = (b * 256 + c * 16) ^ ((b & 7) << 4);
            *(uint4*)((char*)sm.p1.A + off) = v;
        }
        for (int f = t; f < EBLK * nc; f += NTHREADS) {
            int e = f / nc, c = f % nc;
            int dg = h * 128 + c * 8;
            uint4 st = {0u, 0u, 0u, 0u};
            if (dg <= DIM - 8) {
                float4 v0 = E4[(size_t)(e0 + e) * D4 + (dg >> 2)];
                float4 v1 = E4[(size_t)(e0 + e) * D4 + (dg >> 2) + 1];
                st.x = packbf(v0.x, v0.y);
                st.y = packbf(v0.z, v0.w);
                st.z = packbf(v1.x, v1.y);
                st.w = packbf(v1.z, v1.w);
            }
            int off = (e * 256 + c * 16) ^ ((e & 7) << 4);
            *(uint4*)((char*)sm.p1.Bm + off) = st;
        }
        __syncthreads();

        const int nst = h ? 3 : 4;
        const int arow = 16 * w + l15;
        const int aswz = (arow & 7) << 4;
        const int bswz = (l15 & 7) << 4;
        #pragma unroll
        for (int s = 0; s < 4; ++s) {
            if (s < nst) {
                int kb = s * 64 + lq * 16;
                bf16x8 af = *(const bf16x8*)((const char*)sm.p1.A + ((arow * 256 + kb) ^ aswz));
                bf16x8 b0 = *(const bf16x8*)((const char*)sm.p1.Bm + ((l15 * 256 + kb) ^ bswz));
                bf16x8 b1 = *(const bf16x8*)((const char*)sm.p1.Bm + (((16 + l15) * 256 + kb) ^ bswz));
                acc0 = __builtin_amdgcn_mfma_f32_16x16x32_bf16(af, b0, acc0, 0, 0, 0);
                acc1 = __builtin_amdgcn_mfma_f32_16x16x32_bf16(af, b1, acc1, 0, 0, 0);
            }
        }
        __syncthreads();
    }

    // ======== phase 1.5: scatter acc via probed coords, gather at r3 map ====
    #pragma unroll
    for (int r = 0; r < 4; ++r) {
        sm.scat[(ib0[r] >> 8) * 33 + (ib0[r] & 255)] = acc0[r];
        sm.scat[(ib1[r] >> 8) * 33 + (ib1[r] & 255)] = acc1[r];
    }
    __syncthreads();

    // r3 thread mapping: tx = t&7 (4 e each), ty = t>>3 (2 b each)
    const int tx = t & 7;
    const int ty = t >> 3;
    float2 acc2[4];
    #pragma unroll
    for (int j = 0; j < 4; ++j) {
        acc2[j].x = sm.scat[(2 * ty) * 33 + 4 * tx + j];
        acc2[j].y = sm.scat[(2 * ty + 1) * 33 + 4 * tx + j];
    }
    __syncthreads();

    // ============ phase 2: r3/r6 VERBATIM — 4 l-quarters (28/28/28/16) ============
    const float4* N4 = (const float4*)num_lit;
    const float4* C4 = (const float4*)cvec;
    const float4* W4 = (const float4*)nfw;

    #pragma unroll
    for (int q = 0; q < 4; ++q) {
        const int ol  = q * 28;
        const int ol4 = q * 7;
        const int nl4 = (q < 3) ? 7 : 4;
        // xsT: lanes own consecutive e
        for (int f = t; f < EBLK * nl4; f += NTHREADS) {
            int e = f & 31;
            int l4 = f >> 5;
            float4 v = N4[(e0 + e) * 25 + ol4 + l4];
            int lg = ol + 4 * l4;
            sm.p2.xsT[4 * l4 + 0][e] = v.x * sS[lg + 0];
            sm.p2.xsT[4 * l4 + 1][e] = v.y * sS[lg + 1];
            sm.p2.xsT[4 * l4 + 2][e] = v.z * sS[lg + 2];
            sm.p2.xsT[4 * l4 + 3][e] = v.w * sS[lg + 3];
        }
        // asT: lanes own consecutive b
        for (int f = t; f < NB * nl4; f += NTHREADS) {
            int b = f & 63;
            int l4 = f >> 6;
            float4 v = N4[sIdxE[b] * 25 + ol4 + l4];
            float4 cc = C4[ol4 + l4];
            int lg = ol + 4 * l4;
            sm.p2.asT[4 * l4 + 0][b] = (v.x - cc.x) * sS[lg + 0];
            sm.p2.asT[4 * l4 + 1][b] = (v.y - cc.y) * sS[lg + 1];
            sm.p2.asT[4 * l4 + 2][b] = (v.z - cc.z) * sS[lg + 2];
            sm.p2.asT[4 * l4 + 3][b] = (v.w - cc.w) * sS[lg + 3];
        }
        // wT: lanes own consecutive b
        for (int f = t; f < NB * nl4; f += NTHREADS) {
            int b = f & 63;
            int l4 = f >> 6;
            float4 v = W4[sIdxR[b] * 25 + ol4 + l4];
            sm.p2.wT[4 * l4 + 0][b] = v.x;
            sm.p2.wT[4 * l4 + 1][b] = v.y;
            sm.p2.wT[4 * l4 + 2][b] = v.z;
            sm.p2.wT[4 * l4 + 3][b] = v.w;
        }
        __syncthreads();

        const int nl = 4 * nl4;  // 28 or 16
        #pragma unroll 4
        for (int l = 0; l < nl; ++l) {
            float4 xs = *(const float4*)&sm.p2.xsT[l][4 * tx];
            float2 as = *(const float2*)&sm.p2.asT[l][2 * ty];
            float2 w2 = *(const float2*)&sm.p2.wT[l][2 * ty];
            float xj[4] = { xs.x, xs.y, xs.z, xs.w };
            #pragma unroll
            for (int j = 0; j < 4; ++j) {
                float m0 = as.x - xj[j];
                float m1 = as.y - xj[j];
                float p0 = __builtin_amdgcn_exp2f(-(m0 * m0));
                float p1 = __builtin_amdgcn_exp2f(-(m1 * m1));
                acc2[j].x = fmaf(p0, w2.x, acc2[j].x);
                acc2[j].y = fmaf(p1, w2.y, acc2[j].y);
            }
        }
        __syncthreads();
    }

    // ============ epilogue: r3/r6 VERBATIM — sigmoid + float4 stores ============
    {
        float4 o0, o1;
        float* p0 = (float*)&o0;
        float* p1 = (float*)&o1;
        #pragma unroll
        for (int j = 0; j < 4; ++j) {
            float ex0 = __builtin_amdgcn_exp2f(-LOG2E * acc2[j].x);
            float ex1 = __builtin_amdgcn_exp2f(-LOG2E * acc2[j].y);
            p0[j] = __builtin_amdgcn_rcpf(1.0f + ex0);
            p1[j] = __builtin_amdgcn_rcpf(1.0f + ex1);
        }
        size_t b0 = 2 * ty;
        *(float4*)&out[b0 * NE + e0 + 4 * tx] = o0;
        *(float4*)&out[(b0 + 1) * NE + e0 + 4 * tx] = o1;
    }
}

extern "C" void kernel_launch(void* const* d_in, const int* in_sizes, int n_in,
                              void* d_out, int out_size, void* d_ws, size_t ws_size,
                              hipStream_t stream) {
    const int*   e1_idx  = (const int*)d_in[0];
    const int*   r_idx   = (const int*)d_in[1];
    const float* Ew      = (const float*)d_in[2];
    const float* Rw      = (const float*)d_in[3];
    const float* num_lit = (const float*)d_in[4];
    const float* cvec    = (const float*)d_in[5];
    const float* var     = (const float*)d_in[6];
    const float* nfw     = (const float*)d_in[7];
    float* out = (float*)d_out;

    DistMult_prep_kernel<<<8, NTHREADS, 0, stream>>>(
        e1_idx, r_idx, Ew, Rw, (unsigned char*)d_ws);
    DistMult_KBLN_79164837200204_kernel<<<NE / EBLK, NTHREADS, 0, stream>>>(
        e1_idx, r_idx, Ew, num_lit, cvec, var, nfw,
        (const unsigned char*)d_ws, out);
}